// Round 6
// baseline (346.780 us; speedup 1.0000x reference)
//
#include <hip/hip_runtime.h>
#include <hip/hip_bf16.h>

// CoPE, bf16 I/O (device-detected; f32 path kept). dur_us carries ~234us of
// harness fill/restore floor; our budget is the kernels themselves (~100us).
//
// Session lessons:
//  - R1: wave-per-row k2 (16 cols/lane serial) REGRESSED +18.6us — long
//    serial per-lane chains lose. Keep 4 cols/thread per row.
//  - R2: detect folded into k1: -1.3us. Launch overhead ~1-3us/kernel.
//  - R3: __builtin_amdgcn_update_dpp args MUST be literal constants ->
//    template parameters.
//  - R5: DPP scan + clamp fast path: only -1.8us. k2's DS/VALU ops were
//    hidden under memory latency => k2 is LATENCY-bound (runs ~2.4TB/s vs
//    6.7TB/s proven by the fill kernel). Instruction-count work is done.
//
// This round (k2 only): 2 rows per block, both rows' attn + li loads issued
// back-to-back BEFORE any wait -> doubles in-flight read bytes per CU
// (~18KB -> ~36KB) without lengthening any serial chain (each row keeps the
// proven 4-cols/thread shape; the second row is an independent ILP chain).
// __launch_bounds__(256,8) pins <=64 VGPR so occupancy stays 32 waves/CU.

__device__ __forceinline__ float bf2f(unsigned short u) {
    union { unsigned int i; float f; } t; t.i = ((unsigned int)u) << 16; return t.f;
}
__device__ __forceinline__ float bf2f_lo(unsigned int v) {
    union { unsigned int i; float f; } t; t.i = v << 16; return t.f;
}
__device__ __forceinline__ float bf2f_hi(unsigned int v) {
    union { unsigned int i; float f; } t; t.i = v & 0xffff0000u; return t.f;
}
__device__ __forceinline__ unsigned short f2bf(float f) {
    union { float f; unsigned int i; } t; t.f = f;
    unsigned int lsb = (t.i >> 16) & 1u;
    t.i += 0x7fffu + lsb;
    return (unsigned short)(t.i >> 16);
}
__device__ __forceinline__ float sigmoid_fast(float x) {
    float e = __builtin_amdgcn_exp2f(-1.44269504f * x);
    return __builtin_amdgcn_rcpf(1.0f + e);
}

// DPP helper: x + shifted(x). Control words are TEMPLATE constants (the
// builtin requires literal constant args — R3 compile failure). bound_ctrl=1
// gives 0 for out-of-range sources; masked-out rows get old=0 (unchanged add).
template <int CTRL, int ROW_MASK>
__device__ __forceinline__ float dpp_add(float x) {
    int s = __builtin_amdgcn_update_dpp(0, __float_as_int(x), CTRL, ROW_MASK, 0xf, true);
    return x + __int_as_float(s);
}
// Inclusive add-scan across 64 lanes, all on the VALU pipe (no DS ops).
__device__ __forceinline__ float wave_incl_scan(float x) {
    x = dpp_add<0x111, 0xf>(x);   // row_shr:1
    x = dpp_add<0x112, 0xf>(x);   // row_shr:2
    x = dpp_add<0x114, 0xf>(x);   // row_shr:4
    x = dpp_add<0x118, 0xf>(x);   // row_shr:8  -> scan within 16-lane rows
    x = dpp_add<0x142, 0xa>(x);   // row_bcast:15 -> rows 1,3
    x = dpp_add<0x143, 0xc>(x);   // row_bcast:31 -> rows 2,3
    return x;
}

// Standalone detect — only used on the fallback (ws too small) path.
__global__ __launch_bounds__(256) void cope_detect(
    const unsigned short* __restrict__ q, int* __restrict__ flag)
{
    const int tid = threadIdx.x;
    unsigned short u = q[2 * tid];
    int e = (u >> 7) & 0xFF;
    unsigned long long m = __ballot(e >= 200);
    __shared__ int cnt;
    if (tid == 0) cnt = 0;
    __syncthreads();
    if ((tid & 63) == 0) atomicAdd(&cnt, __popcll(m));
    __syncthreads();
    if (tid == 0) *flag = (cnt > 8) ? 1 : 0;   // 1 => float32 buffers
}

// ---------------------------------------------------------------------------
// k1: li[r][n] = sum_d q[r][d] * pe[d][n].  64 rows/block, 256 thr, 4x4 tile.
// Detects dtype inline (same 1KB of q in every block -> consistent verdict);
// block 0 publishes flag for k2.
// ---------------------------------------------------------------------------
__global__ __launch_bounds__(256) void cope_li(
    const void* __restrict__ qv, const void* __restrict__ pev,
    float* __restrict__ li, int* __restrict__ flag)
{
    __shared__ float pe_f[64 * 64];   // [d][n]
    __shared__ float q_t[64 * 64];    // [d][r_local]
    __shared__ int cnt;
    const int tid = threadIdx.x;

    {
        unsigned short u = reinterpret_cast<const unsigned short*>(qv)[2 * tid];
        int e = (u >> 7) & 0xFF;
        unsigned long long m = __ballot(e >= 200);
        if (tid == 0) cnt = 0;
        __syncthreads();
        if ((tid & 63) == 0) atomicAdd(&cnt, __popcll(m));
        __syncthreads();
    }
    const bool isf32 = (cnt > 8);
    if (blockIdx.x == 0 && tid == 0) *flag = isf32 ? 1 : 0;   // for k2

    if (isf32) {
        const float4* pe4 = reinterpret_cast<const float4*>(pev);
#pragma unroll
        for (int it = 0; it < 4; ++it)
            reinterpret_cast<float4*>(pe_f)[it * 256 + tid] = pe4[it * 256 + tid];
        const float4* q4 = reinterpret_cast<const float4*>(qv) + (size_t)blockIdx.x * 1024;
#pragma unroll
        for (int it = 0; it < 4; ++it) {
            int idx = it * 256 + tid;
            int d4 = idx >> 6, rr = idx & 63;
            float4 v = q4[rr * 16 + d4];
            q_t[(d4 * 4 + 0) * 64 + rr] = v.x;
            q_t[(d4 * 4 + 1) * 64 + rr] = v.y;
            q_t[(d4 * 4 + 2) * 64 + rr] = v.z;
            q_t[(d4 * 4 + 3) * 64 + rr] = v.w;
        }
    } else {
        const uint4* pe16 = reinterpret_cast<const uint4*>(pev);
#pragma unroll
        for (int it = 0; it < 2; ++it) {
            int idx = it * 256 + tid;       // 512 uint4 = 4096 bf16
            uint4 v = pe16[idx];
            float4 a, b;
            a.x = bf2f_lo(v.x); a.y = bf2f_hi(v.x);
            a.z = bf2f_lo(v.y); a.w = bf2f_hi(v.y);
            b.x = bf2f_lo(v.z); b.y = bf2f_hi(v.z);
            b.z = bf2f_lo(v.w); b.w = bf2f_hi(v.w);
            float4* dst = reinterpret_cast<float4*>(&pe_f[idx * 8]);
            dst[0] = a; dst[1] = b;
        }
        const ushort4* q4 = reinterpret_cast<const ushort4*>(qv) + (size_t)blockIdx.x * 1024;
#pragma unroll
        for (int it = 0; it < 4; ++it) {
            int idx = it * 256 + tid;
            int d4 = idx >> 6, rr = idx & 63;
            ushort4 v = q4[rr * 16 + d4];
            q_t[(d4 * 4 + 0) * 64 + rr] = bf2f(v.x);
            q_t[(d4 * 4 + 1) * 64 + rr] = bf2f(v.y);
            q_t[(d4 * 4 + 2) * 64 + rr] = bf2f(v.z);
            q_t[(d4 * 4 + 3) * 64 + rr] = bf2f(v.w);
        }
    }
    __syncthreads();

    const int r0 = (tid & 15) * 4, n0 = (tid >> 4) * 4;
    float acc[4][4];
#pragma unroll
    for (int a = 0; a < 4; ++a)
#pragma unroll
        for (int b = 0; b < 4; ++b) acc[a][b] = 0.f;

#pragma unroll 8
    for (int d = 0; d < 64; ++d) {
        float4 qv4 = *reinterpret_cast<const float4*>(&q_t[d * 64 + r0]);
        float4 pv = *reinterpret_cast<const float4*>(&pe_f[d * 64 + n0]);
        acc[0][0] += qv4.x * pv.x; acc[0][1] += qv4.x * pv.y; acc[0][2] += qv4.x * pv.z; acc[0][3] += qv4.x * pv.w;
        acc[1][0] += qv4.y * pv.x; acc[1][1] += qv4.y * pv.y; acc[1][2] += qv4.y * pv.z; acc[1][3] += qv4.y * pv.w;
        acc[2][0] += qv4.z * pv.x; acc[2][1] += qv4.z * pv.y; acc[2][2] += qv4.z * pv.z; acc[2][3] += qv4.z * pv.w;
        acc[3][0] += qv4.w * pv.x; acc[3][1] += qv4.w * pv.y; acc[3][2] += qv4.w * pv.z; acc[3][3] += qv4.w * pv.w;
    }
#pragma unroll
    for (int a = 0; a < 4; ++a) {
        size_t row = (size_t)blockIdx.x * 64 + r0 + a;
        float4 o; o.x = acc[a][0]; o.y = acc[a][1]; o.z = acc[a][2]; o.w = acc[a][3];
        *reinterpret_cast<float4*>(&li[row * 64 + n0]) = o;
    }
}

// ---------------------------------------------------------------------------
// k2: 1 block = 2 rows, 256 threads, 4 cols/thread PER ROW (two independent
// chains). All 4 global loads (attn r0, attn r1, li r0, li r1) issue before
// any wait -> 2x in-flight bytes. One barrier. DPP scans. Per-row clamp
// fast path.
// ---------------------------------------------------------------------------
__global__ __launch_bounds__(256, 8) void cope_row2(
    const void* __restrict__ attnv,
    const float* __restrict__ li_ws,
    void* __restrict__ outv,
    const int* __restrict__ flag)
{
    const int r0 = blockIdx.x * 2;          // rows even (49152)
    const int r1 = r0 + 1;
    const int tid = threadIdx.x;
    const int lane = tid & 63;
    const int wid = tid >> 6;
    const bool isf32 = (*flag != 0);

    __shared__ float li[2][65];             // per-row, +1 pad (li[64]=li[63])
    __shared__ float wsum[2][4];

    // li staging: wave 0 -> row0, wave 1 -> row1 (independent, issue early)
    if (tid < 128) {
        const int w = tid >> 6, c = tid & 63;
        float lv = li_ws[(size_t)(r0 + w) * 64 + c];
        li[w][c] = lv;
        if (c == 63) li[w][64] = lv;
    }

    float g0[4], g1[4];
    if (isf32) {
        const float4* a4 = reinterpret_cast<const float4*>(attnv);
        float4 v0 = a4[(size_t)r0 * 256 + tid];
        float4 v1 = a4[(size_t)r1 * 256 + tid];
        g0[0] = sigmoid_fast(v0.x); g0[1] = sigmoid_fast(v0.y);
        g0[2] = sigmoid_fast(v0.z); g0[3] = sigmoid_fast(v0.w);
        g1[0] = sigmoid_fast(v1.x); g1[1] = sigmoid_fast(v1.y);
        g1[2] = sigmoid_fast(v1.z); g1[3] = sigmoid_fast(v1.w);
    } else {
        const ushort4* a4 = reinterpret_cast<const ushort4*>(attnv);
        ushort4 v0 = a4[(size_t)r0 * 256 + tid];
        ushort4 v1 = a4[(size_t)r1 * 256 + tid];
        g0[0] = sigmoid_fast(bf2f(v0.x)); g0[1] = sigmoid_fast(bf2f(v0.y));
        g0[2] = sigmoid_fast(bf2f(v0.z)); g0[3] = sigmoid_fast(bf2f(v0.w));
        g1[0] = sigmoid_fast(bf2f(v1.x)); g1[1] = sigmoid_fast(bf2f(v1.y));
        g1[2] = sigmoid_fast(bf2f(v1.z)); g1[3] = sigmoid_fast(bf2f(v1.w));
    }

    const int j0 = tid * 4;
    const int i0 = r0 & 1023;               // diagonal cols (i1 = i0+1, no wrap)
    const int i1 = r1 & 1023;
    if (i0 >= j0 && i0 < j0 + 4) g0[i0 - j0] = 0.f;
    if (i1 >= j0 && i1 < j0 + 4) g1[i1 - j0] = 0.f;

    float ts0 = g0[0] + g0[1] + g0[2] + g0[3];
    float ts1 = g1[0] + g1[1] + g1[2] + g1[3];

    // two independent DPP scans (interleave on the VALU pipe)
    float x0 = wave_incl_scan(ts0);
    float x1 = wave_incl_scan(ts1);
    if (lane == 63) { wsum[0][wid] = x0; wsum[1][wid] = x1; }

    __syncthreads();                        // li + wsum visible

    // ---- row 0 ----
    {
        const float s0 = wsum[0][0], s1 = wsum[0][1], s2 = wsum[0][2], s3 = wsum[0][3];
        const float total = s0 + s1 + s2 + s3;
        float woff = 0.f;
        if (wid > 0) woff += s0;
        if (wid > 1) woff += s1;
        if (wid > 2) woff += s2;
        float run = woff + (x0 - ts0);
        const float pl = total - (run + ts0 - g0[3]);
        if (__all(pl >= 63.f)) {
            const float c = li[0][63];
            if (isf32) {
                float4 ov; ov.x = c; ov.y = c; ov.z = c; ov.w = c;
                reinterpret_cast<float4*>(outv)[(size_t)r0 * 256 + tid] = ov;
            } else {
                unsigned cb = (unsigned)f2bf(c); cb |= cb << 16;
                uint2 ov; ov.x = cb; ov.y = cb;
                reinterpret_cast<uint2*>(outv)[(size_t)r0 * 256 + tid] = ov;
            }
        } else {
            float o[4];
#pragma unroll
            for (int e = 0; e < 4; ++e) {
                float p = total - run;
                run += g0[e];
                p = fminf(fmaxf(p, 0.f), 63.f);
                float pf = floorf(p);
                int ipf = (int)pf;
                float a = li[0][ipf], b = li[0][ipf + 1];
                o[e] = fmaf(p - pf, b - a, a);
            }
            if (isf32) {
                float4 ov; ov.x = o[0]; ov.y = o[1]; ov.z = o[2]; ov.w = o[3];
                reinterpret_cast<float4*>(outv)[(size_t)r0 * 256 + tid] = ov;
            } else {
                uint2 ov;
                ov.x = (unsigned)f2bf(o[0]) | ((unsigned)f2bf(o[1]) << 16);
                ov.y = (unsigned)f2bf(o[2]) | ((unsigned)f2bf(o[3]) << 16);
                reinterpret_cast<uint2*>(outv)[(size_t)r0 * 256 + tid] = ov;
            }
        }
    }
    // ---- row 1 ----
    {
        const float s0 = wsum[1][0], s1 = wsum[1][1], s2 = wsum[1][2], s3 = wsum[1][3];
        const float total = s0 + s1 + s2 + s3;
        float woff = 0.f;
        if (wid > 0) woff += s0;
        if (wid > 1) woff += s1;
        if (wid > 2) woff += s2;
        float run = woff + (x1 - ts1);
        const float pl = total - (run + ts1 - g1[3]);
        if (__all(pl >= 63.f)) {
            const float c = li[1][63];
            if (isf32) {
                float4 ov; ov.x = c; ov.y = c; ov.z = c; ov.w = c;
                reinterpret_cast<float4*>(outv)[(size_t)r1 * 256 + tid] = ov;
            } else {
                unsigned cb = (unsigned)f2bf(c); cb |= cb << 16;
                uint2 ov; ov.x = cb; ov.y = cb;
                reinterpret_cast<uint2*>(outv)[(size_t)r1 * 256 + tid] = ov;
            }
        } else {
            float o[4];
#pragma unroll
            for (int e = 0; e < 4; ++e) {
                float p = total - run;
                run += g1[e];
                p = fminf(fmaxf(p, 0.f), 63.f);
                float pf = floorf(p);
                int ipf = (int)pf;
                float a = li[1][ipf], b = li[1][ipf + 1];
                o[e] = fmaf(p - pf, b - a, a);
            }
            if (isf32) {
                float4 ov; ov.x = o[0]; ov.y = o[1]; ov.z = o[2]; ov.w = o[3];
                reinterpret_cast<float4*>(outv)[(size_t)r1 * 256 + tid] = ov;
            } else {
                uint2 ov;
                ov.x = (unsigned)f2bf(o[0]) | ((unsigned)f2bf(o[1]) << 16);
                ov.y = (unsigned)f2bf(o[2]) | ((unsigned)f2bf(o[3]) << 16);
                reinterpret_cast<uint2*>(outv)[(size_t)r1 * 256 + tid] = ov;
            }
        }
    }
}

// ---------------------------------------------------------------------------
// Fallback (ws too small): round-2 fused kernel, known-passing.
// ---------------------------------------------------------------------------
__global__ __launch_bounds__(256) void cope_fused(
    const void* __restrict__ qv, const void* __restrict__ attnv,
    const void* __restrict__ pev, void* __restrict__ outv,
    const int* __restrict__ flag)
{
    const int r = blockIdx.x;
    const int i = r & 1023;
    const int tid = threadIdx.x;
    const int lane = tid & 63;
    const int wid = tid >> 6;
    const bool isf32 = (*flag != 0);

    __shared__ float pe_f[64 * 64];
    __shared__ float q_s[64];
    __shared__ float li[64];
    __shared__ float wsum[4];

    float g[4];
    if (isf32) {
        const float4* pe4 = reinterpret_cast<const float4*>(pev);
#pragma unroll
        for (int it = 0; it < 4; ++it)
            reinterpret_cast<float4*>(pe_f)[it * 256 + tid] = pe4[it * 256 + tid];
        if (tid < 16) {
            float4 v = reinterpret_cast<const float4*>(qv)[(size_t)r * 16 + tid];
            q_s[tid * 4 + 0] = v.x; q_s[tid * 4 + 1] = v.y;
            q_s[tid * 4 + 2] = v.z; q_s[tid * 4 + 3] = v.w;
        }
        float4 av = reinterpret_cast<const float4*>(attnv)[(size_t)r * 256 + tid];
        g[0] = sigmoid_fast(av.x); g[1] = sigmoid_fast(av.y);
        g[2] = sigmoid_fast(av.z); g[3] = sigmoid_fast(av.w);
    } else {
        const uint4* pe16 = reinterpret_cast<const uint4*>(pev);
#pragma unroll
        for (int it = 0; it < 2; ++it) {
            int idx = it * 256 + tid;
            uint4 v = pe16[idx];
            float4 a, b;
            a.x = bf2f_lo(v.x); a.y = bf2f_hi(v.x);
            a.z = bf2f_lo(v.y); a.w = bf2f_hi(v.y);
            b.x = bf2f_lo(v.z); b.y = bf2f_hi(v.z);
            b.z = bf2f_lo(v.w); b.w = bf2f_hi(v.w);
            float4* dst = reinterpret_cast<float4*>(&pe_f[idx * 8]);
            dst[0] = a; dst[1] = b;
        }
        if (tid < 16) {
            ushort4 v = reinterpret_cast<const ushort4*>(qv)[(size_t)r * 16 + tid];
            q_s[tid * 4 + 0] = bf2f(v.x); q_s[tid * 4 + 1] = bf2f(v.y);
            q_s[tid * 4 + 2] = bf2f(v.z); q_s[tid * 4 + 3] = bf2f(v.w);
        }
        ushort4 av = reinterpret_cast<const ushort4*>(attnv)[(size_t)r * 256 + tid];
        g[0] = sigmoid_fast(bf2f(av.x)); g[1] = sigmoid_fast(bf2f(av.y));
        g[2] = sigmoid_fast(bf2f(av.z)); g[3] = sigmoid_fast(bf2f(av.w));
    }

    const int j0 = tid * 4;
    if (i >= j0 && i < j0 + 4) g[i - j0] = 0.f;
    float ts = g[0] + g[1] + g[2] + g[3];
    float x = ts;
#pragma unroll
    for (int s = 1; s < 64; s <<= 1) {
        float y = __shfl_up(x, s, 64);
        if (lane >= s) x += y;
    }
    if (lane == 63) wsum[wid] = x;
    __syncthreads();
    if (tid < 64) {
        float acc = 0.f;
#pragma unroll
        for (int d = 0; d < 64; ++d) acc += q_s[d] * pe_f[d * 64 + tid];
        li[tid] = acc;
    }
    const float s0 = wsum[0], s1 = wsum[1], s2 = wsum[2], s3 = wsum[3];
    const float total = s0 + s1 + s2 + s3;
    float woff = 0.f;
    if (wid > 0) woff += s0;
    if (wid > 1) woff += s1;
    if (wid > 2) woff += s2;
    float run = woff + (x - ts);
    __syncthreads();

    float o[4];
#pragma unroll
    for (int e = 0; e < 4; ++e) {
        float p = total - run;
        run += g[e];
        p = fminf(fmaxf(p, 0.f), 63.f);
        float pf = floorf(p);
        int ipf = (int)pf;
        int ipc = min(ipf + 1, 63);
        float w = p - pf;
        o[e] = li[ipf] + w * (li[ipc] - li[ipf]);
    }
    if (isf32) {
        float4 ov; ov.x = o[0]; ov.y = o[1]; ov.z = o[2]; ov.w = o[3];
        reinterpret_cast<float4*>(outv)[(size_t)r * 256 + tid] = ov;
    } else {
        ushort4 ov;
        ov.x = f2bf(o[0]); ov.y = f2bf(o[1]); ov.z = f2bf(o[2]); ov.w = f2bf(o[3]);
        reinterpret_cast<ushort4*>(outv)[(size_t)r * 256 + tid] = ov;
    }
}

extern "C" void kernel_launch(void* const* d_in, const int* in_sizes, int n_in,
                              void* d_out, int out_size, void* d_ws, size_t ws_size,
                              hipStream_t stream) {
    const void* q    = d_in[0];
    const void* attn = d_in[1];
    const void* pe   = d_in[2];
    int* flag = (int*)d_ws;
    float* li = (float*)((char*)d_ws + 256);

    const long L = 1024;
    const long rows = (long)in_sizes[1] / L;   // 49152 (even)
    const size_t ws_need = 256 + (size_t)rows * 64 * sizeof(float);

    if (ws_size >= ws_need && (rows & 1) == 0) {
        // detect folded into k1; k1 block 0 publishes flag for k2
        cope_li<<<(int)(rows / 64), 256, 0, stream>>>(q, pe, li, flag);
        cope_row2<<<(int)(rows / 2), 256, 0, stream>>>(attn, li, d_out, flag);
    } else {
        cope_detect<<<1, 256, 0, stream>>>((const unsigned short*)d_in[0], flag);
        cope_fused<<<(int)rows, 256, 0, stream>>>(q, attn, pe, d_out, flag);
    }
}